// Round 1
// baseline (450.212 us; speedup 1.0000x reference)
//
#include <hip/hip_runtime.h>
#include <hip/hip_bf16.h>

// Problem constants (fixed by the reference)
#define N_CURVES 2097152   // B*G*C
#define NG       16384     // B*G groups
#define B_PIC    256
#define G_PER_B  64
#define NSLOT    64        // contention-spreading slots for BN12 stats

__device__ __forceinline__ float leaky(float v) {
    // leaky_relu slope 0.01: max(v, 0.01v) is exact for both signs
    return fmaxf(v, 0.01f * v);
}

// ---------------------------------------------------------------------------
// Kernel A: per-curve MLP 32->24->12 (leaky), emit per-group sums of h (pre-BN)
// and 64-slot-spread global sums / sums-of-squares per channel for BN stats.
// BN commutes with the segment mean (affine), so h is never materialized.
//
// R3 changes vs R2 (theory: kill block-wide lockstep; kA is wave-private):
//  - PER-WAVE staging: each wave DMAs exactly its own 8KB quarter
//    (slots 512*wave + 64*i + lane) and waits with a per-wave
//    `s_waitcnt vmcnt(0)` (inline asm + sched_barrier(0)) instead of
//    __syncthreads. Swizzle invariant preserved: LDS unit u holds global
//    float4  8*(u>>3) + ((u&7)^((u>>3)&7)), so the phase-2 read
//    xs[tid*8 + (j^(tid&7))] still yields curve tid's word j.
//  - h2 is stored into the wave's OWN quarter (it has fully consumed its x
//    by then; program order + LDS aliasing keeps read-before-write). The
//    second barrier disappears too; ONE __syncthreads remains (before tail).
//  - h2 stride padded 14 -> 15 floats: gcd(15,32)=1 so the 12 ds_write_b32
//    go from 4-way to 2-way bank aliasing (2-way is free per m136); tail
//    reads stay <=2-way (per-wave region offset 2048 floats = 0 mod 32).
// ---------------------------------------------------------------------------
__global__ __launch_bounds__(256, 5) void kA(const float* __restrict__ x,
                                             const float* __restrict__ w1,
                                             const float* __restrict__ b1,
                                             const float* __restrict__ w2,
                                             const float* __restrict__ b2,
                                             float* __restrict__ partials,   // [NSLOT][24]
                                             float* __restrict__ groupSums)  // [NG][12]
{
    // 32 KB LDS. Wave w owns bytes [8192*w, 8192*(w+1)):
    //   phase 1 = 512 float4 of swizzled x, phase 2 = 64 x 15-float h2 rows.
    __shared__ __align__(16) char smem[32768];
    float4* xs = (float4*)smem;

    const int tid  = threadIdx.x;
    const int lane = tid & 63;
    const int wave = tid >> 6;
    const size_t blockBase = (size_t)blockIdx.x * 2048;   // float4 index of block's x
    const float4* __restrict__ xg = (const float4*)x;

    // ---- phase 1: per-wave global -> LDS DMA (swizzle on the global side) ----
    // Wave w, iter i covers LDS units [512w + 64i, +64): a contiguous, perfectly
    // coalesced 1KB global segment (permutation is within 128B chunks only).
#pragma unroll
    for (int i = 0; i < 8; ++i) {
        const int s = wave * 512 + i * 64 + lane;  // this lane's LDS float4 slot
        const int c = s >> 3;
        const int j = (s & 7) ^ (c & 7);           // global chunk-word for this slot
        const float4* gp = xg + blockBase + c * 8 + j;
        // wave-uniform LDS base; DMA writes base + lane*16
        float4* lp = xs + (wave * 512 + i * 64);
#if defined(__has_builtin) && __has_builtin(__builtin_amdgcn_global_load_lds)
        __builtin_amdgcn_global_load_lds(
            (const __attribute__((address_space(1))) void*)gp,
            (__attribute__((address_space(3))) void*)lp, 16, 0, 0);
#else
        xs[s] = *gp;   // fallback: same wave-private destination, no race
#endif
    }
    // Per-wave wait: only THIS wave's 8 DMA loads must land (its quarter is
    // written exclusively by itself). No block-wide barrier / no lockstep.
    asm volatile("s_waitcnt vmcnt(0)" ::: "memory");
    __builtin_amdgcn_sched_barrier(0);   // rule 18: pin consumers behind the wait

    // ---- per-curve read (swizzled => all 8 bank-groups hit once per 8 lanes) ----
    float xr[32];
#pragma unroll
    for (int j = 0; j < 8; ++j) {
        const float4 v = xs[tid * 8 + (j ^ (tid & 7))];
        xr[4 * j + 0] = v.x; xr[4 * j + 1] = v.y;
        xr[4 * j + 2] = v.z; xr[4 * j + 3] = v.w;
    }

    // ---- fused MLP: layer1 row j retires straight into layer2 accumulators ----
    float h2[12];
#pragma unroll
    for (int c = 0; c < 12; ++c) h2[c] = b2[c];
#pragma unroll
    for (int j = 0; j < 24; ++j) {
        float t = b1[j];
#pragma unroll
        for (int k = 0; k < 32; ++k) t = fmaf(xr[k], w1[j * 32 + k], t);
        t = leaky(t);
#pragma unroll
        for (int c = 0; c < 12; ++c) h2[c] = fmaf(t, w2[c * 24 + j], h2[c]);
    }
    // h2 lands in the wave's OWN quarter (x there is already consumed by us)
    float* smw = (float*)smem + wave * 2048;     // 2048 floats = 8KB per wave
#pragma unroll
    for (int c = 0; c < 12; ++c) {
        h2[c] = leaky(h2[c]);
        smw[lane * 15 + c] = h2[c];              // stride 15: 2-way banks (free)
    }
    __syncthreads();   // the single remaining barrier: publish h2 for the tail

    // ---- one-wave tail: 24 jobs (group g in {0,1} x channel c in [0,12)) ----
    // group g = curves [128g,128g+128) = waves {2g, 2g+1}; per-wave region
    // offset is 2048 floats = 0 mod 32, so banks depend only on (15*i + c):
    // 24 threads -> <=2-way per bank (free).
    if (tid < 24) {
        const int c = tid % 12;
        const int g = tid / 12;
        const float* sb = (const float*)smem;
        float S0 = 0.f, S1 = 0.f, S2 = 0.f, S3 = 0.f;
        float Q0 = 0.f, Q1 = 0.f, Q2 = 0.f, Q3 = 0.f;
#pragma unroll
        for (int wv = 0; wv < 2; ++wv) {
            const float* base = sb + (size_t)(g * 2 + wv) * 2048 + c;
#pragma unroll 8
            for (int i = 0; i < 64; i += 4) {
                const float v0 = base[(i + 0) * 15];
                const float v1 = base[(i + 1) * 15];
                const float v2 = base[(i + 2) * 15];
                const float v3 = base[(i + 3) * 15];
                S0 += v0; Q0 = fmaf(v0, v0, Q0);
                S1 += v1; Q1 = fmaf(v1, v1, Q1);
                S2 += v2; Q2 = fmaf(v2, v2, Q2);
                S3 += v3; Q3 = fmaf(v3, v3, Q3);
            }
        }
        const float S = (S0 + S1) + (S2 + S3);
        const float Q = (Q0 + Q1) + (Q2 + Q3);
        groupSums[(size_t)(2 * blockIdx.x + g) * 12 + c] = S;
        const int slot = blockIdx.x & (NSLOT - 1);  // spread contention 64x
        atomicAdd(&partials[slot * 24 + c], S);          // 2-way (g0+g1) per addr
        atomicAdd(&partials[slot * 24 + 12 + c], Q);
    }
}

// ---------------------------------------------------------------------------
// Kernel B: one wave per picture. Finalize BN12, cor = leaky(dist@wd.T+bd),
// three pooling levels, write sum_pic[b][36] = [L1 | L2 | L3].
// ---------------------------------------------------------------------------
__global__ __launch_bounds__(64) void kB(const float* __restrict__ partials,
                                         const float* __restrict__ groupSums,
                                         const float* __restrict__ dist,     // [B][G][2][5]
                                         const float* __restrict__ wd,       // [12][5]
                                         const float* __restrict__ bd,
                                         const float* __restrict__ gamma12,
                                         const float* __restrict__ beta12,
                                         float* __restrict__ sum_pic)        // [B][36]
{
    __shared__ float scale[12], shift[12];
    const int g = threadIdx.x;      // group within picture
    const int b = blockIdx.x;       // picture

    if (g < 12) {
        float S = 0.f, Q = 0.f;
#pragma unroll 8
        for (int s = 0; s < NSLOT; ++s) {
            S += partials[s * 24 + g];
            Q += partials[s * 24 + 12 + g];
        }
        const float mu  = S * (1.0f / (float)N_CURVES);
        const float var = Q * (1.0f / (float)N_CURVES) - mu * mu;  // biased, matches ref
        const float inv = rsqrtf(var + 1e-5f);
        scale[g] = inv * gamma12[g];
        shift[g] = beta12[g] - mu * inv * gamma12[g];
    }
    __syncthreads();

    const float* dm = dist + (size_t)(b * G_PER_B + g) * 2 * 5;  // [.,.,0,:]
    const float d0 = dm[0], d1 = dm[1], d2 = dm[2], d3 = dm[3], d4 = dm[4];
    const float* gs = groupSums + (size_t)(b * G_PER_B + g) * 12;

    float a1[12], a2[12], a3[12];
#pragma unroll
    for (int d = 0; d < 12; ++d) {
        float cor = bd[d];
        cor = fmaf(d0, wd[d * 5 + 0], cor);
        cor = fmaf(d1, wd[d * 5 + 1], cor);
        cor = fmaf(d2, wd[d * 5 + 2], cor);
        cor = fmaf(d3, wd[d * 5 + 3], cor);
        cor = fmaf(d4, wd[d * 5 + 4], cor);
        cor = leaky(cor);
        float t = gs[d] * (1.0f / 128.0f);       // group mean (pre-BN)
        t = t * scale[d] + shift[d];             // BN12 applied post-mean (affine commute)
        a1[d] = t;
        a2[d] = cor * t;
        a3[d] = cor * cor * t;
    }

    // reduce the 36 accumulators over the 64 groups (single wave)
#pragma unroll
    for (int d = 0; d < 12; ++d) {
        float v1 = a1[d], v2 = a2[d], v3 = a3[d];
#pragma unroll
        for (int off = 32; off >= 1; off >>= 1) {
            v1 += __shfl_down(v1, off);
            v2 += __shfl_down(v2, off);
            v3 += __shfl_down(v3, off);
        }
        if (g == 0) {
            sum_pic[b * 36 + d]      = v1 * (1.0f / 64.0f);
            sum_pic[b * 36 + 12 + d] = v2 * (1.0f / 64.0f);
            sum_pic[b * 36 + 24 + d] = v3 * (1.0f / 64.0f);
        }
    }
}

// ---------------------------------------------------------------------------
// Kernel C: single block. BN36 over the 256 pictures, then 36->18->8->2 MLP
// + softmax. Thread t owns picture t. Output: p2 (256x8) then p3 (256x2).
// ---------------------------------------------------------------------------
__global__ __launch_bounds__(256) void kC(const float* __restrict__ sum_pic,
                                          const float* __restrict__ gamma36,
                                          const float* __restrict__ beta36,
                                          const float* __restrict__ wp1,
                                          const float* __restrict__ bp1,
                                          const float* __restrict__ wp2,
                                          const float* __restrict__ bp2,
                                          const float* __restrict__ wp3,
                                          const float* __restrict__ bp3,
                                          float* __restrict__ out)
{
    const int t = threadIdx.x;  // picture
    __shared__ float sm[256 * 37];      // padded: bank = (37t+c)%32, 5 coprime 32
    __shared__ float scale[36], shift[36];

    float s[36];
#pragma unroll
    for (int c = 0; c < 36; ++c) {
        s[c] = sum_pic[t * 36 + c];
        sm[t * 37 + c] = s[c];
    }
    __syncthreads();

    if (t < 36) {
        float S = 0.f, Q = 0.f;
        for (int i = 0; i < 256; ++i) {
            const float v = sm[i * 37 + t];
            S += v;
            Q += v * v;
        }
        const float m   = S * (1.0f / 256.0f);
        const float inv = rsqrtf(Q * (1.0f / 256.0f) - m * m + 1e-5f);
        scale[t] = inv * gamma36[t];
        shift[t] = beta36[t] - m * inv * gamma36[t];
    }
    __syncthreads();

#pragma unroll
    for (int c = 0; c < 36; ++c)
        s[c] = s[c] * scale[c] + shift[c];

    float p1[18];
#pragma unroll
    for (int j = 0; j < 18; ++j) {
        float acc = bp1[j];
#pragma unroll
        for (int k = 0; k < 36; ++k) acc = fmaf(s[k], wp1[j * 36 + k], acc);
        p1[j] = leaky(acc);
    }
    float p2[8];
#pragma unroll
    for (int j = 0; j < 8; ++j) {
        float acc = bp2[j];
#pragma unroll
        for (int k = 0; k < 18; ++k) acc = fmaf(p1[k], wp2[j * 18 + k], acc);
        p2[j] = leaky(acc);
    }
    float l0 = bp3[0], l1 = bp3[1];
#pragma unroll
    for (int k = 0; k < 8; ++k) {
        l0 = fmaf(p2[k], wp3[k], l0);
        l1 = fmaf(p2[k], wp3[8 + k], l1);
    }
    const float m  = fmaxf(l0, l1);
    const float e0 = __expf(l0 - m);
    const float e1 = __expf(l1 - m);
    const float rd = 1.0f / (e0 + e1);

#pragma unroll
    for (int j = 0; j < 8; ++j) out[t * 8 + j] = p2[j];   // p2 block: [0, 2048)
    out[2048 + t * 2 + 0] = e0 * rd;                       // p3 block: [2048, 2560)
    out[2048 + t * 2 + 1] = e1 * rd;
}

extern "C" void kernel_launch(void* const* d_in, const int* in_sizes, int n_in,
                              void* d_out, int out_size, void* d_ws, size_t ws_size,
                              hipStream_t stream) {
    const float* x       = (const float*)d_in[0];
    const float* dist    = (const float*)d_in[1];
    // d_in[2] segment_ids: arange(N)//C -> uniform contiguous segments; implicit in indexing
    const float* w1      = (const float*)d_in[3];
    const float* b1      = (const float*)d_in[4];
    const float* w2      = (const float*)d_in[5];
    const float* b2      = (const float*)d_in[6];
    const float* gamma12 = (const float*)d_in[7];
    const float* beta12  = (const float*)d_in[8];
    const float* wd      = (const float*)d_in[9];
    const float* bd      = (const float*)d_in[10];
    const float* gamma36 = (const float*)d_in[11];
    const float* beta36  = (const float*)d_in[12];
    const float* wp1     = (const float*)d_in[13];
    const float* bp1     = (const float*)d_in[14];
    const float* wp2     = (const float*)d_in[15];
    const float* bp2     = (const float*)d_in[16];
    const float* wp3     = (const float*)d_in[17];
    const float* bp3     = (const float*)d_in[18];

    float* ws        = (float*)d_ws;
    float* partials  = ws;                          // NSLOT*24 floats
    float* groupSums = ws + NSLOT * 24;             // NG*12 floats
    float* sum_pic   = groupSums + (size_t)NG * 12; // B_PIC*36 floats

    // ws is re-poisoned to 0xAA before every launch; zero only the atomic targets
    hipMemsetAsync(partials, 0, NSLOT * 24 * sizeof(float), stream);

    kA<<<N_CURVES / 256, 256, 0, stream>>>(x, w1, b1, w2, b2, partials, groupSums);
    kB<<<B_PIC, G_PER_B, 0, stream>>>(partials, groupSums, dist, wd, bd,
                                      gamma12, beta12, sum_pic);
    kC<<<1, 256, 0, stream>>>(sum_pic, gamma36, beta36,
                              wp1, bp1, wp2, bp2, wp3, bp3, (float*)d_out);
}